// Round 1
// baseline (6150.424 us; speedup 1.0000x reference)
//
#include <hip/hip_runtime.h>
#include <math.h>

// Problem constants (match reference shapes)
#define Bb 4
#define Ss 4096
#define Hh 1024
#define Mm 1024
#define Ee 16
#define CAPk 512            // ceil(2.0 * 4096 / 16)

#define TS 64               // GEMM tile (M and N)
#define KS 16               // GEMM K-tile

__device__ __forceinline__ float silu_f(float x) {
    return x / (1.0f + expf(-x));
}

// ---------------- router ----------------

// tlogit[b,e] = sum_h timestep[b,h] * gate_w[h, e]   (first-H rows of gate_w)
__global__ __launch_bounds__(64)
void tlogit_kernel(const float* __restrict__ timestep,
                   const float* __restrict__ gate_w,
                   float* __restrict__ tlogit) {
    int be = blockIdx.x;            // 0..63
    int b = be >> 4, e = be & 15;
    int lane = threadIdx.x;         // 0..63
    float p = 0.f;
#pragma unroll
    for (int j = 0; j < 16; ++j) {
        int h = lane + 64 * j;
        p += timestep[b * Hh + h] * gate_w[h * Ee + e];
    }
#pragma unroll
    for (int off = 32; off; off >>= 1) p += __shfl_xor(p, off);
    if (lane == 0) tlogit[be] = p;
}

// scores[b,e,s] = sigmoid(tlogit[b,e] + hsu[b,s,:] . gate_w[H:, e])
__global__ __launch_bounds__(256)
void scores_kernel(const float* __restrict__ hsu,
                   const float* __restrict__ gate_w,
                   const float* __restrict__ tlogit,
                   float* __restrict__ scores) {
    __shared__ float row[Hh];
    int token = blockIdx.x;               // 0..B*S-1
    int b = token >> 12;                  // /4096
    int s = token & (Ss - 1);
    const float* hr = hsu + (size_t)token * Hh;
    for (int i = threadIdx.x; i < Hh; i += 256) row[i] = hr[i];
    __syncthreads();
    int lane = threadIdx.x & 63, w = threadIdx.x >> 6;
    const float* gw2 = gate_w + (size_t)Hh * Ee;  // second-half rows
#pragma unroll
    for (int ei = 0; ei < 4; ++ei) {
        int e = w * 4 + ei;
        float p = 0.f;
#pragma unroll
        for (int j = 0; j < 16; ++j) {
            int h = lane + 64 * j;
            p += row[h] * gw2[h * Ee + e];
        }
#pragma unroll
        for (int off = 32; off; off >>= 1) p += __shfl_xor(p, off);
        if (lane == 0) {
            float logit = tlogit[b * Ee + e] + p;
            scores[((size_t)(b * Ee + e)) * Ss + s] = 1.f / (1.f + expf(-logit));
        }
    }
}

// ---------------- expert-choice top-k (radix select, 512 of 4096) ----------------
// Tie-break: values > T all selected; among values == T, smallest s indices
// selected first (matches jax.lax.top_k semantics). Slot order within (b,e)
// is irrelevant to the final output (pure permutation of rows).
__global__ __launch_bounds__(256)
void topk_kernel(const float* __restrict__ scores,
                 int* __restrict__ sel_idx,
                 float* __restrict__ sel_gate) {
    const int be = blockIdx.x;
    const float* sc = scores + (size_t)be * Ss;
    const int t = threadIdx.x;
    __shared__ unsigned hist[256];
    __shared__ unsigned sh_prefix;
    __shared__ int sh_need;
    __shared__ unsigned eqoff[256];
    __shared__ unsigned cnt_gt;

    unsigned vu[16];
#pragma unroll
    for (int i = 0; i < 16; ++i) vu[i] = __float_as_uint(sc[t * 16 + i]);

    unsigned prefix = 0;
    int need = CAPk;
    for (int pass = 0; pass < 4; ++pass) {
        const int shift = 24 - 8 * pass;
        hist[t] = 0;
        __syncthreads();
#pragma unroll
        for (int i = 0; i < 16; ++i) {
            unsigned u = vu[i];
            bool ok = (pass == 0) || ((u >> (shift + 8)) == prefix);
            if (ok) atomicAdd(&hist[(u >> shift) & 255u], 1u);
        }
        __syncthreads();
        if (t == 0) {
            int nd = need;
            int bin = 255;
            for (; bin >= 0; --bin) {
                int c = (int)hist[bin];
                if (c < nd) nd -= c; else break;
            }
            sh_prefix = (prefix << 8) | (unsigned)bin;
            sh_need = nd;
        }
        __syncthreads();
        prefix = sh_prefix;
        need = sh_need;
        __syncthreads();
    }
    const unsigned T = prefix;
    const int need_eq = need;                 // # equals to take
    const unsigned ngt = (unsigned)(CAPk - need_eq);

    int myeq = 0;
#pragma unroll
    for (int i = 0; i < 16; ++i) myeq += (vu[i] == T) ? 1 : 0;
    eqoff[t] = (unsigned)myeq;
    if (t == 0) cnt_gt = 0;
    __syncthreads();
    if (t == 0) {
        unsigned run = 0;
        for (int j = 0; j < 256; ++j) { unsigned c = eqoff[j]; eqoff[j] = run; run += c; }
    }
    __syncthreads();
    unsigned eqr = eqoff[t];
#pragma unroll
    for (int i = 0; i < 16; ++i) {
        unsigned u = vu[i];
        int s = t * 16 + i;
        if (u > T) {
            unsigned slot = atomicAdd(&cnt_gt, 1u);
            sel_idx[(size_t)be * CAPk + slot] = s;
            sel_gate[(size_t)be * CAPk + slot] = __uint_as_float(u);
        } else if (u == T) {
            if ((int)eqr < need_eq) {
                unsigned slot = ngt + eqr;
                sel_idx[(size_t)be * CAPk + slot] = s;
                sel_gate[(size_t)be * CAPk + slot] = __uint_as_float(u);
            }
            eqr++;
        }
    }
}

// ---------------- normalization ----------------

__global__ void zero_kernel(float* p, int n) {
    int i = blockIdx.x * 256 + threadIdx.x;
    if (i < n) p[i] = 0.f;
}

__global__ void accum_kernel(const int* __restrict__ sel_idx,
                             const float* __restrict__ sel_gate,
                             float* __restrict__ sums) {
    int g = blockIdx.x * 256 + threadIdx.x;   // 0..B*E*CAP-1
    int be = g / CAPk;
    int b = be >> 4;
    atomicAdd(&sums[b * Ss + sel_idx[g]], sel_gate[g]);
}

// Produce per-expert-contiguous slot arrays: [e][b][cap]
__global__ void finalize_kernel(const int* __restrict__ sel_idx,
                                const float* __restrict__ sel_gate,
                                const float* __restrict__ sums,
                                int* __restrict__ slot_token,
                                float* __restrict__ slot_w) {
    int g = blockIdx.x * 256 + threadIdx.x;
    int be = g / CAPk, c = g % CAPk;
    int b = be >> 4, e = be & 15;
    int token = b * Ss + sel_idx[g];
    float wv = sel_gate[g] / (sums[token] + 1e-12f);   // * ROUTE_SCALE(=1)
    int o = (e * Bb + b) * CAPk + c;
    slot_token[o] = token;
    slot_w[o] = wv;
}

// ---------------- GEMM1 (x @ W1 -> fused SwiGLU activation) ----------------
// Computes act[m, n] for n in [0,1024): needs W1 columns n and n+1024.
// GATHER: rows via slot_token (per-expert), W1 = gate_up_proj[e].
// SILU_FIRST: act = silu(c1)*c2 (routed)  else  act = c1*silu(c2) (shared).
template <bool GATHER, bool SILU_FIRST>
__global__ __launch_bounds__(256)
void gemm1_kernel(const float* __restrict__ X,       // [B*S, H]
                  const float* __restrict__ Wbase,
                  const int* __restrict__ slot_token,
                  float* __restrict__ act,
                  int row_base, int e_base) {
    __shared__ float As[KS][TS + 1];
    __shared__ float Bs1[KS][TS + 1];
    __shared__ float Bs2[KS][TS + 1];
    __shared__ int rows[TS];

    const int t = threadIdx.x;
    const int bx = blockIdx.x, by = blockIdx.y, bz = blockIdx.z;
    const int m0 = by * TS;
    const int n0 = bx * TS;

    const float* W;
    size_t act_off;
    if (GATHER) {
        int e = e_base + bz;
        W = Wbase + (size_t)e * Hh * (2 * Mm);
        if (t < TS) rows[t] = slot_token[e * (Bb * CAPk) + m0 + t];
        act_off = ((size_t)bz * (Bb * CAPk) + m0) * Mm;
    } else {
        W = Wbase;
        if (t < TS) rows[t] = row_base + m0 + t;
        act_off = (size_t)m0 * Mm;
    }
    __syncthreads();

    float acc1[4][4] = {{0.f}}, acc2[4][4] = {{0.f}};
    const int tx = t & 15, ty = t >> 4;

    for (int k0 = 0; k0 < Hh; k0 += KS) {
#pragma unroll
        for (int i = 0; i < 4; ++i) {
            int lin = i * 256 + t;
            int m = lin >> 4, k = lin & 15;
            As[k][m] = X[(size_t)rows[m] * Hh + (k0 + k)];
        }
#pragma unroll
        for (int i = 0; i < 4; ++i) {
            int lin = i * 256 + t;
            int k = lin >> 6, n = lin & 63;
            const float* wr = W + (size_t)(k0 + k) * (2 * Mm);
            Bs1[k][n] = wr[n0 + n];
            Bs2[k][n] = wr[n0 + n + Mm];
        }
        __syncthreads();
#pragma unroll
        for (int kk = 0; kk < KS; ++kk) {
            float a[4], b1[4], b2[4];
#pragma unroll
            for (int i = 0; i < 4; ++i) a[i] = As[kk][ty * 4 + i];
#pragma unroll
            for (int j = 0; j < 4; ++j) { b1[j] = Bs1[kk][tx * 4 + j]; b2[j] = Bs2[kk][tx * 4 + j]; }
#pragma unroll
            for (int i = 0; i < 4; ++i)
#pragma unroll
                for (int j = 0; j < 4; ++j) {
                    acc1[i][j] += a[i] * b1[j];
                    acc2[i][j] += a[i] * b2[j];
                }
        }
        __syncthreads();
    }
#pragma unroll
    for (int i = 0; i < 4; ++i) {
        float* arow = act + act_off + (size_t)(ty * 4 + i) * Mm + n0;
#pragma unroll
        for (int j = 0; j < 4; ++j) {
            float c1 = acc1[i][j], c2 = acc2[i][j];
            float v = SILU_FIRST ? silu_f(c1) * c2 : c1 * silu_f(c2);
            arow[tx * 4 + j] = v;
        }
    }
}

// ---------------- GEMM2 (act @ W2 -> out) ----------------
// SCATTER: out[token] += acc * slot_w (atomic);  else plain store (shared expert).
template <bool SCATTER>
__global__ __launch_bounds__(256)
void gemm2_kernel(const float* __restrict__ act,
                  const float* __restrict__ W2base,
                  const int* __restrict__ slot_token,
                  const float* __restrict__ slot_w,
                  float* __restrict__ out,
                  int row_base, int e_base) {
    __shared__ float As[KS][TS + 1];
    __shared__ float Bs[KS][TS + 1];
    __shared__ int rows[TS];
    __shared__ float wgt[TS];

    const int t = threadIdx.x;
    const int bx = blockIdx.x, by = blockIdx.y, bz = blockIdx.z;
    const int m0 = by * TS;
    const int n0 = bx * TS;

    const float* W2;
    size_t a_off;
    if (SCATTER) {
        int e = e_base + bz;
        W2 = W2base + (size_t)e * Mm * Hh;
        if (t < TS) {
            rows[t] = slot_token[e * (Bb * CAPk) + m0 + t];
            wgt[t] = slot_w[e * (Bb * CAPk) + m0 + t];
        }
        a_off = ((size_t)bz * (Bb * CAPk) + m0) * Mm;
    } else {
        W2 = W2base;
        a_off = (size_t)m0 * Mm;
    }
    __syncthreads();

    float acc[4][4] = {{0.f}};
    const int tx = t & 15, ty = t >> 4;

    for (int k0 = 0; k0 < Mm; k0 += KS) {
#pragma unroll
        for (int i = 0; i < 4; ++i) {
            int lin = i * 256 + t;
            int m = lin >> 4, k = lin & 15;
            As[k][m] = act[a_off + (size_t)m * Mm + (k0 + k)];
        }
#pragma unroll
        for (int i = 0; i < 4; ++i) {
            int lin = i * 256 + t;
            int k = lin >> 6, n = lin & 63;
            Bs[k][n] = W2[(size_t)(k0 + k) * Hh + n0 + n];
        }
        __syncthreads();
#pragma unroll
        for (int kk = 0; kk < KS; ++kk) {
            float a[4], b[4];
#pragma unroll
            for (int i = 0; i < 4; ++i) a[i] = As[kk][ty * 4 + i];
#pragma unroll
            for (int j = 0; j < 4; ++j) b[j] = Bs[kk][tx * 4 + j];
#pragma unroll
            for (int i = 0; i < 4; ++i)
#pragma unroll
                for (int j = 0; j < 4; ++j) acc[i][j] += a[i] * b[j];
        }
        __syncthreads();
    }
#pragma unroll
    for (int i = 0; i < 4; ++i) {
        int m = ty * 4 + i;
        if (SCATTER) {
            int token = rows[m];
            float wv = wgt[m];
#pragma unroll
            for (int j = 0; j < 4; ++j)
                atomicAdd(&out[(size_t)token * Hh + n0 + tx * 4 + j], acc[i][j] * wv);
        } else {
#pragma unroll
            for (int j = 0; j < 4; ++j)
                out[(size_t)(row_base + m0 + m) * Hh + n0 + tx * 4 + j] = acc[i][j];
        }
    }
}

// ---------------- host launcher ----------------

extern "C" void kernel_launch(void* const* d_in, const int* in_sizes, int n_in,
                              void* d_out, int out_size, void* d_ws, size_t ws_size,
                              hipStream_t stream) {
    const float* hidden   = (const float*)d_in[0];
    const float* hsu      = (const float*)d_in[1];
    const float* timestep = (const float*)d_in[2];
    const float* gate_w   = (const float*)d_in[3];
    const float* gate_up  = (const float*)d_in[4];
    const float* down     = (const float*)d_in[5];
    const float* sh_gu    = (const float*)d_in[6];
    const float* sh_dn    = (const float*)d_in[7];
    float* out = (float*)d_out;

    char* ws = (char*)d_ws;
    float* tlogit = (float*)ws;      ws += 1024;
    float* scores = (float*)ws;      ws += (size_t)Bb * Ee * Ss * 4;
    int* sel_idx = (int*)ws;         ws += (size_t)Bb * Ee * CAPk * 4;
    float* sel_gate = (float*)ws;    ws += (size_t)Bb * Ee * CAPk * 4;
    float* sums = (float*)ws;        ws += (size_t)Bb * Ss * 4;
    int* slot_token = (int*)ws;      ws += (size_t)Ee * Bb * CAPk * 4;
    float* slot_w = (float*)ws;      ws += (size_t)Ee * Bb * CAPk * 4;
    float* act = (float*)ws;
    size_t used = (size_t)(ws - (char*)d_ws);
    size_t act_avail = ws_size > used ? ws_size - used : 0;

    // --- router ---
    tlogit_kernel<<<Bb * Ee, 64, 0, stream>>>(timestep, gate_w, tlogit);
    scores_kernel<<<Bb * Ss, 256, 0, stream>>>(hsu, gate_w, tlogit, scores);
    topk_kernel<<<Bb * Ee, 256, 0, stream>>>(scores, sel_idx, sel_gate);
    zero_kernel<<<(Bb * Ss + 255) / 256, 256, 0, stream>>>(sums, Bb * Ss);
    accum_kernel<<<(Bb * Ee * CAPk) / 256, 256, 0, stream>>>(sel_idx, sel_gate, sums);
    finalize_kernel<<<(Bb * Ee * CAPk) / 256, 256, 0, stream>>>(sel_idx, sel_gate, sums,
                                                                slot_token, slot_w);

    // --- shared expert (chunked over rows to fit workspace) ---
    long long max_rows_ll = (long long)(act_avail / ((size_t)Mm * 4));
    int max_rows = (int)(max_rows_ll > (Bb * Ss) ? (Bb * Ss) : max_rows_ll);
    max_rows &= ~63;
    if (max_rows < 64) max_rows = 64;  // assume ws_size is at least ~2 MB

    for (int r0 = 0; r0 < Bb * Ss; r0 += max_rows) {
        int rows = Bb * Ss - r0;
        if (rows > max_rows) rows = max_rows;
        dim3 g1(Mm / TS, rows / TS, 1);
        gemm1_kernel<false, false><<<g1, 256, 0, stream>>>(hidden, sh_gu, nullptr, act, r0, 0);
        dim3 g2(Hh / TS, rows / TS, 1);
        gemm2_kernel<false><<<g2, 256, 0, stream>>>(act, sh_dn, nullptr, nullptr, out, r0, 0);
    }

    // --- routed experts (grouped to fit workspace) ---
    const int rows_per_e = Bb * CAPk;  // 2048
    int ge = max_rows / rows_per_e;
    if (ge < 1) ge = 1;
    if (ge > Ee) ge = Ee;
    for (int e0 = 0; e0 < Ee; e0 += ge) {
        int g = Ee - e0;
        if (g > ge) g = ge;
        dim3 g1(Mm / TS, rows_per_e / TS, g);
        gemm1_kernel<true, true><<<g1, 256, 0, stream>>>(hidden, gate_up, slot_token, act, 0, e0);
        dim3 g2(Hh / TS, rows_per_e / TS, g);
        gemm2_kernel<true><<<g2, 256, 0, stream>>>(act, down, slot_token, slot_w, out, 0, e0);
    }
}

// Round 2
// 1336.067 us; speedup vs baseline: 4.6034x; 4.6034x over previous
//
#include <hip/hip_runtime.h>
#include <math.h>

// Problem constants
#define Bb 4
#define Ss 4096
#define Hh 1024
#define Mm 1024
#define Ee 16
#define CAPk 512            // ceil(2.0 * 4096 / 16)

typedef unsigned short u16;
typedef __attribute__((ext_vector_type(8))) short short8;
typedef __attribute__((ext_vector_type(4))) float floatx4;
typedef __attribute__((ext_vector_type(4))) unsigned short ushort4v;

__device__ __forceinline__ float silu_f(float x) {
    return x / (1.0f + expf(-x));
}

// fp32 -> bf16 (RNE)
__device__ __forceinline__ u16 f2b(float x) {
    union { float f; unsigned u; } v; v.f = x;
    unsigned r = (v.u + 0x7fffu + ((v.u >> 16) & 1u)) >> 16;
    return (u16)r;
}

// async 16B global->LDS (wave-uniform LDS base + lane*16)
__device__ __forceinline__ void gl_lds16(const u16* g, u16* l) {
    __builtin_amdgcn_global_load_lds((const __attribute__((address_space(1))) void*)g,
                                     (__attribute__((address_space(3))) void*)l, 16, 0, 0);
}

// ---------------- router (fp32, unchanged from round 1 — selection must stay exact) ----------------

__global__ __launch_bounds__(64)
void tlogit_kernel(const float* __restrict__ timestep,
                   const float* __restrict__ gate_w,
                   float* __restrict__ tlogit) {
    int be = blockIdx.x;
    int b = be >> 4, e = be & 15;
    int lane = threadIdx.x;
    float p = 0.f;
#pragma unroll
    for (int j = 0; j < 16; ++j) {
        int h = lane + 64 * j;
        p += timestep[b * Hh + h] * gate_w[h * Ee + e];
    }
#pragma unroll
    for (int off = 32; off; off >>= 1) p += __shfl_xor(p, off);
    if (lane == 0) tlogit[be] = p;
}

__global__ __launch_bounds__(256)
void scores_kernel(const float* __restrict__ hsu,
                   const float* __restrict__ gate_w,
                   const float* __restrict__ tlogit,
                   float* __restrict__ scores) {
    __shared__ float row[Hh];
    int token = blockIdx.x;
    int b = token >> 12;
    int s = token & (Ss - 1);
    const float* hr = hsu + (size_t)token * Hh;
    for (int i = threadIdx.x; i < Hh; i += 256) row[i] = hr[i];
    __syncthreads();
    int lane = threadIdx.x & 63, w = threadIdx.x >> 6;
    const float* gw2 = gate_w + (size_t)Hh * Ee;
#pragma unroll
    for (int ei = 0; ei < 4; ++ei) {
        int e = w * 4 + ei;
        float p = 0.f;
#pragma unroll
        for (int j = 0; j < 16; ++j) {
            int h = lane + 64 * j;
            p += row[h] * gw2[h * Ee + e];
        }
#pragma unroll
        for (int off = 32; off; off >>= 1) p += __shfl_xor(p, off);
        if (lane == 0) {
            float logit = tlogit[b * Ee + e] + p;
            scores[((size_t)(b * Ee + e)) * Ss + s] = 1.f / (1.f + expf(-logit));
        }
    }
}

__global__ __launch_bounds__(256)
void topk_kernel(const float* __restrict__ scores,
                 int* __restrict__ sel_idx,
                 float* __restrict__ sel_gate) {
    const int be = blockIdx.x;
    const float* sc = scores + (size_t)be * Ss;
    const int t = threadIdx.x;
    __shared__ unsigned hist[256];
    __shared__ unsigned sh_prefix;
    __shared__ int sh_need;
    __shared__ unsigned eqoff[256];
    __shared__ unsigned cnt_gt;

    unsigned vu[16];
#pragma unroll
    for (int i = 0; i < 16; ++i) vu[i] = __float_as_uint(sc[t * 16 + i]);

    unsigned prefix = 0;
    int need = CAPk;
    for (int pass = 0; pass < 4; ++pass) {
        const int shift = 24 - 8 * pass;
        hist[t] = 0;
        __syncthreads();
#pragma unroll
        for (int i = 0; i < 16; ++i) {
            unsigned u = vu[i];
            bool ok = (pass == 0) || ((u >> (shift + 8)) == prefix);
            if (ok) atomicAdd(&hist[(u >> shift) & 255u], 1u);
        }
        __syncthreads();
        if (t == 0) {
            int nd = need;
            int bin = 255;
            for (; bin >= 0; --bin) {
                int c = (int)hist[bin];
                if (c < nd) nd -= c; else break;
            }
            sh_prefix = (prefix << 8) | (unsigned)bin;
            sh_need = nd;
        }
        __syncthreads();
        prefix = sh_prefix;
        need = sh_need;
        __syncthreads();
    }
    const unsigned T = prefix;
    const int need_eq = need;
    const unsigned ngt = (unsigned)(CAPk - need_eq);

    int myeq = 0;
#pragma unroll
    for (int i = 0; i < 16; ++i) myeq += (vu[i] == T) ? 1 : 0;
    eqoff[t] = (unsigned)myeq;
    if (t == 0) cnt_gt = 0;
    __syncthreads();
    if (t == 0) {
        unsigned run = 0;
        for (int j = 0; j < 256; ++j) { unsigned c = eqoff[j]; eqoff[j] = run; run += c; }
    }
    __syncthreads();
    unsigned eqr = eqoff[t];
#pragma unroll
    for (int i = 0; i < 16; ++i) {
        unsigned u = vu[i];
        int s = t * 16 + i;
        if (u > T) {
            unsigned slot = atomicAdd(&cnt_gt, 1u);
            sel_idx[(size_t)be * CAPk + slot] = s;
            sel_gate[(size_t)be * CAPk + slot] = __uint_as_float(u);
        } else if (u == T) {
            if ((int)eqr < need_eq) {
                unsigned slot = ngt + eqr;
                sel_idx[(size_t)be * CAPk + slot] = s;
                sel_gate[(size_t)be * CAPk + slot] = __uint_as_float(u);
            }
            eqr++;
        }
    }
}

__global__ void zero_kernel(float* p, int n) {
    int i = blockIdx.x * 256 + threadIdx.x;
    if (i < n) p[i] = 0.f;
}

__global__ void accum_kernel(const int* __restrict__ sel_idx,
                             const float* __restrict__ sel_gate,
                             float* __restrict__ sums) {
    int g = blockIdx.x * 256 + threadIdx.x;
    int be = g / CAPk;
    int b = be >> 4;
    atomicAdd(&sums[b * Ss + sel_idx[g]], sel_gate[g]);
}

__global__ void finalize_kernel(const int* __restrict__ sel_idx,
                                const float* __restrict__ sel_gate,
                                const float* __restrict__ sums,
                                int* __restrict__ slot_token,
                                float* __restrict__ slot_w) {
    int g = blockIdx.x * 256 + threadIdx.x;
    int be = g / CAPk, c = g % CAPk;
    int b = be >> 4, e = be & 15;
    int token = b * Ss + sel_idx[g];
    float wv = sel_gate[g] / (sums[token] + 1e-12f);
    int o = (e * Bb + b) * CAPk + c;
    slot_token[o] = token;
    slot_w[o] = wv;
}

// ---------------- conversion / transpose / gather ----------------

// flat fp32 -> bf16, 4 elems/thread
__global__ __launch_bounds__(256)
void convert_bf16(const float* __restrict__ src, u16* __restrict__ dst) {
    int i = (blockIdx.x * 256 + threadIdx.x) * 4;
    float4 v = *(const float4*)(src + i);
    ushort4v o = { f2b(v.x), f2b(v.y), f2b(v.z), f2b(v.w) };
    *(ushort4v*)(dst + i) = o;
}

// W[k][n] fp32 (K=1024 rows, N cols) -> Wt[n][k] bf16 (ld 1024), batched over z
__global__ __launch_bounds__(256)
void transpose_bf16(const float* __restrict__ W, u16* __restrict__ Wt,
                    int N, size_t zsrc, size_t zdst) {
    __shared__ float tile[32][33];
    int n0 = blockIdx.x * 32, k0 = blockIdx.y * 32, z = blockIdx.z;
    const float* Ws = W + (size_t)z * zsrc;
    u16* Wd = Wt + (size_t)z * zdst;
    int tn = threadIdx.x & 31, tk = threadIdx.x >> 5;   // tk 0..7
#pragma unroll
    for (int i = 0; i < 4; ++i)
        tile[tk + i * 8][tn] = Ws[(size_t)(k0 + tk + i * 8) * N + n0 + tn];
    __syncthreads();
#pragma unroll
    for (int i = 0; i < 4; ++i)
        Wd[(size_t)(n0 + tk + i * 8) * 1024 + k0 + tn] = f2b(tile[tn][tk + i * 8]);
}

// gather routed rows -> bf16 contiguous [z*2048 + li][1024]
__global__ __launch_bounds__(256)
void gather_bf16(const float* __restrict__ X, const int* __restrict__ slot_token,
                 u16* __restrict__ Ag, int e0) {
    int z = blockIdx.x >> 11, li = blockIdx.x & 2047;
    int token = slot_token[(e0 + z) * 2048 + li];
    const float* src = X + (size_t)token * 1024;
    u16* dst = Ag + (size_t)blockIdx.x * 1024;
    int i = threadIdx.x * 4;
    float4 v = *(const float4*)(src + i);
    ushort4v o = { f2b(v.x), f2b(v.y), f2b(v.z), f2b(v.w) };
    *(ushort4v*)(dst + i) = o;
}

// ---------------- MFMA GEMMs (m97-style: 128x128 tile, BK=64, global_load_lds, XOR swizzle) ----------------
// LDS layout per 128x64 bf16 tile: row m (128B) at m*128 bytes; 16B chunk c stored at
// slot (c ^ (m&7)). Staging picks per-lane *source* so dest stays lane-contiguous.

__device__ __forceinline__ void stage_tile(const u16* __restrict__ grow, int k0,
                                           u16* lds, int t) {
#pragma unroll
    for (int r = 0; r < 4; ++r) {
        int o = (r * 256 + t) * 16;            // byte offset in 16KB tile
        int m = o >> 7;                        // row 0..127
        int c = ((o >> 4) & 7) ^ (m & 7);      // global 16B chunk
        const u16* src = grow + (size_t)m * 1024 + k0 + c * 8;
        u16* dst = lds + ((r * 4096 + (t >> 6) * 1024) >> 1);  // wave-uniform
        gl_lds16(src, dst);
    }
}

// GEMM1: act[row][n] = swiglu( A@W1t[n] , A@W1t[n+1024] ), act bf16, n in [0,1024)
template <bool SILU_FIRST>
__global__ __launch_bounds__(256, 2)
void gemm1_mfma(const u16* __restrict__ A, int a_row0, int zstride,
                const u16* __restrict__ W1t, u16* __restrict__ act) {
    __shared__ u16 lA[128 * 64];
    __shared__ u16 lB1[128 * 64];
    __shared__ u16 lB2[128 * 64];
    const int t = threadIdx.x;
    const int n0 = blockIdx.x * 128;
    const int bm0 = blockIdx.y * 128;
    const int z = blockIdx.z;
    const int zb = z * zstride;
    const u16* Arow = A + (size_t)(a_row0 + zb + bm0) * 1024;
    const u16* B1row = W1t + ((size_t)z * 2048 + n0) * 1024;
    const u16* B2row = B1row + (size_t)1024 * 1024;
    const int lane = t & 63;
    const int wv = t >> 6, wm = wv & 1, wn = wv >> 1;
    const int quad = lane >> 4, l15 = lane & 15;

    floatx4 zero4 = {0.f, 0.f, 0.f, 0.f};
    floatx4 acc1[4][4], acc2[4][4];
#pragma unroll
    for (int i = 0; i < 4; ++i)
#pragma unroll
        for (int j = 0; j < 4; ++j) { acc1[i][j] = zero4; acc2[i][j] = zero4; }

    for (int k0 = 0; k0 < 1024; k0 += 64) {
        __syncthreads();
        stage_tile(Arow, k0, lA, t);
        stage_tile(B1row, k0, lB1, t);
        stage_tile(B2row, k0, lB2, t);
        __syncthreads();
#pragma unroll
        for (int kc = 0; kc < 2; ++kc) {
            short8 af[4], bf1[4], bf2[4];
#pragma unroll
            for (int mi = 0; mi < 4; ++mi) {
                int m = wm * 64 + mi * 16 + l15;
                int off = m * 64 + (((kc * 4 + quad) ^ (m & 7)) * 8);
                af[mi] = *(const short8*)&lA[off];
            }
#pragma unroll
            for (int ni = 0; ni < 4; ++ni) {
                int n = wn * 64 + ni * 16 + l15;
                int off = n * 64 + (((kc * 4 + quad) ^ (n & 7)) * 8);
                bf1[ni] = *(const short8*)&lB1[off];
                bf2[ni] = *(const short8*)&lB2[off];
            }
#pragma unroll
            for (int mi = 0; mi < 4; ++mi)
#pragma unroll
                for (int ni = 0; ni < 4; ++ni) {
                    acc1[mi][ni] = __builtin_amdgcn_mfma_f32_16x16x32_bf16(af[mi], bf1[ni], acc1[mi][ni], 0, 0, 0);
                    acc2[mi][ni] = __builtin_amdgcn_mfma_f32_16x16x32_bf16(af[mi], bf2[ni], acc2[mi][ni], 0, 0, 0);
                }
        }
    }
#pragma unroll
    for (int mi = 0; mi < 4; ++mi)
#pragma unroll
        for (int ni = 0; ni < 4; ++ni)
#pragma unroll
            for (int r = 0; r < 4; ++r) {
                int m = wm * 64 + mi * 16 + quad * 4 + r;
                int n = wn * 64 + ni * 16 + l15;
                float c1 = acc1[mi][ni][r], c2 = acc2[mi][ni][r];
                float v = SILU_FIRST ? silu_f(c1) * c2 : c1 * silu_f(c2);
                act[(size_t)(zb + bm0 + m) * 1024 + n0 + n] = f2b(v);
            }
}

// GEMM2: C = A(act,bf16) @ W2t ; plain fp32 store (shared) or weighted atomic scatter (routed)
template <bool SCATTER>
__global__ __launch_bounds__(256, 2)
void gemm2_mfma(const u16* __restrict__ A, int zstride,
                const u16* __restrict__ W2t,
                const int* __restrict__ slot_token, const float* __restrict__ slot_w,
                float* __restrict__ out, int out_row0, int e_base) {
    __shared__ u16 lA[128 * 64];
    __shared__ u16 lB[128 * 64];
    __shared__ int s_tok[128];
    __shared__ float s_w[128];
    const int t = threadIdx.x;
    const int n0 = blockIdx.x * 128;
    const int bm0 = blockIdx.y * 128;
    const int z = blockIdx.z;
    const int zb = z * zstride;
    const u16* Arow = A + (size_t)(zb + bm0) * 1024;
    const u16* Brow = W2t + ((size_t)z * 1024 + n0) * 1024;
    const int lane = t & 63;
    const int wv = t >> 6, wm = wv & 1, wn = wv >> 1;
    const int quad = lane >> 4, l15 = lane & 15;

    if (SCATTER && t < 128) {
        int gi = (e_base + z) * 2048 + bm0 + t;
        s_tok[t] = slot_token[gi];
        s_w[t] = slot_w[gi];
    }

    floatx4 zero4 = {0.f, 0.f, 0.f, 0.f};
    floatx4 acc[4][4];
#pragma unroll
    for (int i = 0; i < 4; ++i)
#pragma unroll
        for (int j = 0; j < 4; ++j) acc[i][j] = zero4;

    for (int k0 = 0; k0 < 1024; k0 += 64) {
        __syncthreads();
        stage_tile(Arow, k0, lA, t);
        stage_tile(Brow, k0, lB, t);
        __syncthreads();
#pragma unroll
        for (int kc = 0; kc < 2; ++kc) {
            short8 af[4], bf[4];
#pragma unroll
            for (int mi = 0; mi < 4; ++mi) {
                int m = wm * 64 + mi * 16 + l15;
                int off = m * 64 + (((kc * 4 + quad) ^ (m & 7)) * 8);
                af[mi] = *(const short8*)&lA[off];
            }
#pragma unroll
            for (int ni = 0; ni < 4; ++ni) {
                int n = wn * 64 + ni * 16 + l15;
                int off = n * 64 + (((kc * 4 + quad) ^ (n & 7)) * 8);
                bf[ni] = *(const short8*)&lB[off];
            }
#pragma unroll
            for (int mi = 0; mi < 4; ++mi)
#pragma unroll
                for (int ni = 0; ni < 4; ++ni)
                    acc[mi][ni] = __builtin_amdgcn_mfma_f32_16x16x32_bf16(af[mi], bf[ni], acc[mi][ni], 0, 0, 0);
        }
    }
#pragma unroll
    for (int mi = 0; mi < 4; ++mi)
#pragma unroll
        for (int ni = 0; ni < 4; ++ni)
#pragma unroll
            for (int r = 0; r < 4; ++r) {
                int m = wm * 64 + mi * 16 + quad * 4 + r;
                int n = wn * 64 + ni * 16 + l15;
                float c = acc[mi][ni][r];
                if (SCATTER) {
                    atomicAdd(&out[(size_t)s_tok[m] * 1024 + n0 + n], c * s_w[m]);
                } else {
                    out[(size_t)(out_row0 + bm0 + m) * 1024 + n0 + n] = c;
                }
            }
}

// ---------------- host launcher ----------------

extern "C" void kernel_launch(void* const* d_in, const int* in_sizes, int n_in,
                              void* d_out, int out_size, void* d_ws, size_t ws_size,
                              hipStream_t stream) {
    const float* hidden   = (const float*)d_in[0];
    const float* hsu      = (const float*)d_in[1];
    const float* timestep = (const float*)d_in[2];
    const float* gate_w   = (const float*)d_in[3];
    const float* gate_up  = (const float*)d_in[4];
    const float* down     = (const float*)d_in[5];
    const float* sh_gu    = (const float*)d_in[6];
    const float* sh_dn    = (const float*)d_in[7];
    float* out = (float*)d_out;

    char* p = (char*)d_ws;
    auto alloc = [&](size_t bytes) { char* r = p; p += (bytes + 255) & ~(size_t)255; return r; };
    float* tlogit    = (float*)alloc((size_t)Bb * Ee * 4);
    float* scores    = (float*)alloc((size_t)Bb * Ee * Ss * 4);
    int*   sel_idx   = (int*)  alloc((size_t)Bb * Ee * CAPk * 4);
    float* sel_gate  = (float*)alloc((size_t)Bb * Ee * CAPk * 4);
    float* sums      = (float*)alloc((size_t)Bb * Ss * 4);
    int*   slot_token= (int*)  alloc((size_t)Ee * Bb * CAPk * 4);
    float* slot_w    = (float*)alloc((size_t)Ee * Bb * CAPk * 4);
    char* phase = p;
    long long avail = (long long)((char*)d_ws + ws_size - phase);
    if (avail < 0) avail = 0;

    // --- router ---
    tlogit_kernel<<<Bb * Ee, 64, 0, stream>>>(timestep, gate_w, tlogit);
    scores_kernel<<<Bb * Ss, 256, 0, stream>>>(hsu, gate_w, tlogit, scores);
    topk_kernel<<<Bb * Ee, 256, 0, stream>>>(scores, sel_idx, sel_gate);
    zero_kernel<<<(Bb * Ss + 255) / 256, 256, 0, stream>>>(sums, Bb * Ss);
    accum_kernel<<<(Bb * Ee * CAPk) / 256, 256, 0, stream>>>(sel_idx, sel_gate, sums);
    finalize_kernel<<<(Bb * Ee * CAPk) / 256, 256, 0, stream>>>(sel_idx, sel_gate, sums,
                                                                slot_token, slot_w);

    // --- shared expert phase (phase scratch: Xb | Wt1s | Wt2s | actS) ---
    {
        u16* Xb   = (u16*)phase;                       // 16384*1024 bf16 = 32 MB
        u16* Wt1s = Xb + (size_t)16384 * 1024;         // 2048*1024 bf16 = 4 MB
        u16* Wt2s = Wt1s + (size_t)2048 * 1024;        // 1024*1024 bf16 = 2 MB
        u16* actS = Wt2s + (size_t)1024 * 1024;
        long long fixed = ((long long)16384 * 1024 + 2048 * 1024 + 1024 * 1024) * 2;
        long long room = (avail - fixed) / 2048;       // act rows
        room &= ~127LL;
        int R = (int)(room > 16384 ? 16384 : room);
        if (R < 128) R = 128;

        convert_bf16<<<16384, 256, 0, stream>>>(hidden, Xb);
        transpose_bf16<<<dim3(64, 32, 1), 256, 0, stream>>>(sh_gu, Wt1s, 2048, 0, 0);
        transpose_bf16<<<dim3(32, 32, 1), 256, 0, stream>>>(sh_dn, Wt2s, 1024, 0, 0);
        for (int r0 = 0; r0 < Bb * Ss; r0 += R) {
            int cur = Bb * Ss - r0; if (cur > R) cur = R;
            gemm1_mfma<false><<<dim3(8, cur / 128, 1), 256, 0, stream>>>(Xb, r0, 0, Wt1s, actS);
            gemm2_mfma<false><<<dim3(8, cur / 128, 1), 256, 0, stream>>>(actS, 0, Wt2s,
                                                                         nullptr, nullptr, out, r0, 0);
        }
    }

    // --- routed experts phase (reuse phase scratch: Ag | Wt1r | Wt2r | actR) ---
    {
        const long long per_e = ((long long)2048 * 1024 * 3 + 1024 * 1024) * 2;  // 14 MB
        int g = (int)(avail / per_e);
        if (g < 1) g = 1;
        if (g > Ee) g = Ee;
        u16* Ag   = (u16*)phase;
        u16* Wt1r = Ag   + (size_t)g * 2048 * 1024;
        u16* Wt2r = Wt1r + (size_t)g * 2048 * 1024;
        u16* actR = Wt2r + (size_t)g * 1024 * 1024;

        for (int e0 = 0; e0 < Ee; e0 += g) {
            int cg = Ee - e0; if (cg > g) cg = g;
            gather_bf16<<<cg * 2048, 256, 0, stream>>>(hidden, slot_token, Ag, e0);
            transpose_bf16<<<dim3(64, 32, cg), 256, 0, stream>>>(
                gate_up + (size_t)e0 * 2097152, Wt1r, 2048, 2097152, 2097152);
            transpose_bf16<<<dim3(32, 32, cg), 256, 0, stream>>>(
                down + (size_t)e0 * 1048576, Wt2r, 1024, 1048576, 1048576);
            gemm1_mfma<true><<<dim3(8, 16, cg), 256, 0, stream>>>(Ag, 0, 2048, Wt1r, actR);
            gemm2_mfma<true><<<dim3(8, 16, cg), 256, 0, stream>>>(actR, 2048, Wt2r,
                                                                  slot_token, slot_w, out, 0, e0);
        }
    }
}

// Round 3
// 879.742 us; speedup vs baseline: 6.9912x; 1.5187x over previous
//
#include <hip/hip_runtime.h>
#include <math.h>

// Problem constants
#define Bb 4
#define Ss 4096
#define Hh 1024
#define Mm 1024
#define Ee 16
#define CAPk 512            // ceil(2.0 * 4096 / 16)

typedef unsigned short u16;
typedef __attribute__((ext_vector_type(8))) short short8;
typedef __attribute__((ext_vector_type(4))) float floatx4;
typedef __attribute__((ext_vector_type(4))) unsigned short ushort4v;

__device__ __forceinline__ float silu_f(float x) {
    return x / (1.0f + expf(-x));
}

// fp32 -> bf16 (RNE)
__device__ __forceinline__ u16 f2b(float x) {
    union { float f; unsigned u; } v; v.f = x;
    unsigned r = (v.u + 0x7fffu + ((v.u >> 16) & 1u)) >> 16;
    return (u16)r;
}

// async 16B global->LDS (wave-uniform LDS base + lane*16)
__device__ __forceinline__ void gl_lds16(const void* g, void* l) {
    __builtin_amdgcn_global_load_lds((const __attribute__((address_space(1))) void*)g,
                                     (__attribute__((address_space(3))) void*)l, 16, 0, 0);
}

// ---------------- router ----------------

__global__ __launch_bounds__(64)
void tlogit_kernel(const float* __restrict__ timestep,
                   const float* __restrict__ gate_w,
                   float* __restrict__ tlogit) {
    int be = blockIdx.x;
    int b = be >> 4, e = be & 15;
    int lane = threadIdx.x;
    float p = 0.f;
#pragma unroll
    for (int j = 0; j < 16; ++j) {
        int h = lane + 64 * j;
        p += timestep[b * Hh + h] * gate_w[h * Ee + e];
    }
#pragma unroll
    for (int off = 32; off; off >>= 1) p += __shfl_xor(p, off);
    if (lane == 0) tlogit[be] = p;
}

// Skinny GEMM: scores[b,e,s] = sigmoid(tlogit[b,e] + hsu[token,:] . gw2[:,e])
// 64 tokens/block (256 blocks), K chunked by 64 via global_load_lds w16.
// Wave w covers experts 4w..4w+3 for all 64 tokens (lane = token) -> Gs reads
// are wave-uniform broadcasts; Xs is XOR-swizzled per 16-token group so
// ds_read_b128 at 256B token stride is conflict-free.
__global__ __launch_bounds__(256)
void router_scores(const float* __restrict__ hsu,
                   const float* __restrict__ gate_w,
                   const float* __restrict__ tlogit,
                   float* __restrict__ scores) {
    __shared__ float Xs[64 * 64];   // 16 KB, swizzled 16B chunks
    __shared__ float Gs[64 * 16];   // 4 KB
    const int t = threadIdx.x;
    const int row0 = blockIdx.x * 64;        // token base (never crosses b: 4096%64==0)
    const int b = row0 >> 12;
    const int wave = t >> 6, lane = t & 63;
    const int e0 = wave * 4;
    const float* gw2 = gate_w + (size_t)Hh * Ee;   // [k][16] second-half rows

    float acc0 = 0.f, acc1 = 0.f, acc2 = 0.f, acc3 = 0.f;

    for (int k0 = 0; k0 < Hh; k0 += 64) {
        __syncthreads();
        // stage X tile: 64 tok x 64 k fp32, 4 rounds of 256 lanes x 16B
#pragma unroll
        for (int r = 0; r < 4; ++r) {
            int tok = r * 16 + (t >> 4);
            int cslot = t & 15;                 // dest 16B slot within row
            int g = cslot ^ (tok & 15);         // source chunk (swizzle via source)
            const float* src = hsu + (size_t)(row0 + tok) * Hh + k0 + g * 4;
            char* dst = (char*)Xs + r * 4096 + wave * 1024;   // wave-uniform
            gl_lds16(src, dst);
        }
        // stage G chunk: 64 k x 16 e fp32 = 4KB = exactly 256 lanes x 16B
        {
            const float* src = gw2 + (size_t)k0 * Ee + t * 4;
            char* dst = (char*)Gs + wave * 1024;
            gl_lds16(src, dst);
        }
        __syncthreads();
#pragma unroll
        for (int kk = 0; kk < 64; kk += 4) {
            int slot = (kk >> 2) ^ (lane & 15);
            float4 a = *(const float4*)&Xs[lane * 64 + slot * 4];
            float4 g0 = *(const float4*)&Gs[(kk + 0) * Ee + e0];
            float4 g1 = *(const float4*)&Gs[(kk + 1) * Ee + e0];
            float4 g2 = *(const float4*)&Gs[(kk + 2) * Ee + e0];
            float4 g3 = *(const float4*)&Gs[(kk + 3) * Ee + e0];
            acc0 += a.x * g0.x; acc0 += a.y * g1.x; acc0 += a.z * g2.x; acc0 += a.w * g3.x;
            acc1 += a.x * g0.y; acc1 += a.y * g1.y; acc1 += a.z * g2.y; acc1 += a.w * g3.y;
            acc2 += a.x * g0.z; acc2 += a.y * g1.z; acc2 += a.z * g2.z; acc2 += a.w * g3.z;
            acc3 += a.x * g0.w; acc3 += a.y * g1.w; acc3 += a.z * g2.w; acc3 += a.w * g3.w;
        }
    }
    const int s = (row0 + lane) & (Ss - 1);
    float l0 = acc0 + tlogit[b * Ee + e0 + 0];
    float l1 = acc1 + tlogit[b * Ee + e0 + 1];
    float l2 = acc2 + tlogit[b * Ee + e0 + 2];
    float l3 = acc3 + tlogit[b * Ee + e0 + 3];
    scores[((size_t)(b * Ee + e0 + 0)) * Ss + s] = 1.f / (1.f + expf(-l0));
    scores[((size_t)(b * Ee + e0 + 1)) * Ss + s] = 1.f / (1.f + expf(-l1));
    scores[((size_t)(b * Ee + e0 + 2)) * Ss + s] = 1.f / (1.f + expf(-l2));
    scores[((size_t)(b * Ee + e0 + 3)) * Ss + s] = 1.f / (1.f + expf(-l3));
}

__global__ __launch_bounds__(256)
void topk_kernel(const float* __restrict__ scores,
                 int* __restrict__ sel_idx,
                 float* __restrict__ sel_gate) {
    const int be = blockIdx.x;
    const float* sc = scores + (size_t)be * Ss;
    const int t = threadIdx.x;
    __shared__ unsigned hist[256];
    __shared__ unsigned sh_prefix;
    __shared__ int sh_need;
    __shared__ unsigned eqoff[256];
    __shared__ unsigned cnt_gt;

    unsigned vu[16];
#pragma unroll
    for (int i = 0; i < 16; ++i) vu[i] = __float_as_uint(sc[t * 16 + i]);

    unsigned prefix = 0;
    int need = CAPk;
    for (int pass = 0; pass < 4; ++pass) {
        const int shift = 24 - 8 * pass;
        hist[t] = 0;
        __syncthreads();
#pragma unroll
        for (int i = 0; i < 16; ++i) {
            unsigned u = vu[i];
            bool ok = (pass == 0) || ((u >> (shift + 8)) == prefix);
            if (ok) atomicAdd(&hist[(u >> shift) & 255u], 1u);
        }
        __syncthreads();
        if (t == 0) {
            int nd = need;
            int bin = 255;
            for (; bin >= 0; --bin) {
                int c = (int)hist[bin];
                if (c < nd) nd -= c; else break;
            }
            sh_prefix = (prefix << 8) | (unsigned)bin;
            sh_need = nd;
        }
        __syncthreads();
        prefix = sh_prefix;
        need = sh_need;
        __syncthreads();
    }
    const unsigned T = prefix;
    const int need_eq = need;
    const unsigned ngt = (unsigned)(CAPk - need_eq);

    int myeq = 0;
#pragma unroll
    for (int i = 0; i < 16; ++i) myeq += (vu[i] == T) ? 1 : 0;
    eqoff[t] = (unsigned)myeq;
    if (t == 0) cnt_gt = 0;
    __syncthreads();
    if (t == 0) {
        unsigned run = 0;
        for (int j = 0; j < 256; ++j) { unsigned c = eqoff[j]; eqoff[j] = run; run += c; }
    }
    __syncthreads();
    unsigned eqr = eqoff[t];
#pragma unroll
    for (int i = 0; i < 16; ++i) {
        unsigned u = vu[i];
        int s = t * 16 + i;
        if (u > T) {
            unsigned slot = atomicAdd(&cnt_gt, 1u);
            sel_idx[(size_t)be * CAPk + slot] = s;
            sel_gate[(size_t)be * CAPk + slot] = __uint_as_float(u);
        } else if (u == T) {
            if ((int)eqr < need_eq) {
                unsigned slot = ngt + eqr;
                sel_idx[(size_t)be * CAPk + slot] = s;
                sel_gate[(size_t)be * CAPk + slot] = __uint_as_float(u);
            }
            eqr++;
        }
    }
}

__global__ void zero_kernel(float* p, int n) {
    int i = blockIdx.x * 256 + threadIdx.x;
    if (i < n) p[i] = 0.f;
}

__global__ void accum_kernel(const int* __restrict__ sel_idx,
                             const float* __restrict__ sel_gate,
                             float* __restrict__ sums) {
    int g = blockIdx.x * 256 + threadIdx.x;
    int be = g / CAPk;
    int b = be >> 4;
    atomicAdd(&sums[b * Ss + sel_idx[g]], sel_gate[g]);
}

__global__ void finalize_kernel(const int* __restrict__ sel_idx,
                                const float* __restrict__ sel_gate,
                                const float* __restrict__ sums,
                                int* __restrict__ slot_token,
                                float* __restrict__ slot_w) {
    int g = blockIdx.x * 256 + threadIdx.x;
    int be = g / CAPk, c = g % CAPk;
    int b = be >> 4, e = be & 15;
    int token = b * Ss + sel_idx[g];
    float wv = sel_gate[g] / (sums[token] + 1e-12f);
    int o = (e * Bb + b) * CAPk + c;
    slot_token[o] = token;
    slot_w[o] = wv;
}

// ---------------- conversion / transpose / gather ----------------

__global__ __launch_bounds__(256)
void convert_bf16(const float* __restrict__ src, u16* __restrict__ dst) {
    int i = (blockIdx.x * 256 + threadIdx.x) * 4;
    float4 v = *(const float4*)(src + i);
    ushort4v o = { f2b(v.x), f2b(v.y), f2b(v.z), f2b(v.w) };
    *(ushort4v*)(dst + i) = o;
}

__global__ __launch_bounds__(256)
void transpose_bf16(const float* __restrict__ W, u16* __restrict__ Wt,
                    int N, size_t zsrc, size_t zdst) {
    __shared__ float tile[32][33];
    int n0 = blockIdx.x * 32, k0 = blockIdx.y * 32, z = blockIdx.z;
    const float* Ws = W + (size_t)z * zsrc;
    u16* Wd = Wt + (size_t)z * zdst;
    int tn = threadIdx.x & 31, tk = threadIdx.x >> 5;   // tk 0..7
#pragma unroll
    for (int i = 0; i < 4; ++i)
        tile[tk + i * 8][tn] = Ws[(size_t)(k0 + tk + i * 8) * N + n0 + tn];
    __syncthreads();
#pragma unroll
    for (int i = 0; i < 4; ++i)
        Wd[(size_t)(n0 + tk + i * 8) * 1024 + k0 + tn] = f2b(tile[tn][tk + i * 8]);
}

__global__ __launch_bounds__(256)
void gather_bf16(const float* __restrict__ X, const int* __restrict__ slot_token,
                 u16* __restrict__ Ag, int e0) {
    int z = blockIdx.x >> 11, li = blockIdx.x & 2047;
    int token = slot_token[(e0 + z) * 2048 + li];
    const float* src = X + (size_t)token * 1024;
    u16* dst = Ag + (size_t)blockIdx.x * 1024;
    int i = threadIdx.x * 4;
    float4 v = *(const float4*)(src + i);
    ushort4v o = { f2b(v.x), f2b(v.y), f2b(v.z), f2b(v.w) };
    *(ushort4v*)(dst + i) = o;
}

// ---------------- MFMA GEMMs (m97-style: 128x128 tile, BK=64, global_load_lds, XOR swizzle) ----------------

__device__ __forceinline__ void stage_tile(const u16* __restrict__ grow, int k0,
                                           u16* lds, int t) {
#pragma unroll
    for (int r = 0; r < 4; ++r) {
        int o = (r * 256 + t) * 16;            // byte offset in 16KB tile
        int m = o >> 7;                        // row 0..127
        int c = ((o >> 4) & 7) ^ (m & 7);      // global 16B chunk
        const u16* src = grow + (size_t)m * 1024 + k0 + c * 8;
        u16* dst = lds + ((r * 4096 + (t >> 6) * 1024) >> 1);  // wave-uniform
        gl_lds16(src, dst);
    }
}

template <bool SILU_FIRST>
__global__ __launch_bounds__(256, 2)
void gemm1_mfma(const u16* __restrict__ A, int a_row0, int zstride,
                const u16* __restrict__ W1t, u16* __restrict__ act) {
    __shared__ u16 lA[128 * 64];
    __shared__ u16 lB1[128 * 64];
    __shared__ u16 lB2[128 * 64];
    const int t = threadIdx.x;
    const int n0 = blockIdx.x * 128;
    const int bm0 = blockIdx.y * 128;
    const int z = blockIdx.z;
    const int zb = z * zstride;
    const u16* Arow = A + (size_t)(a_row0 + zb + bm0) * 1024;
    const u16* B1row = W1t + ((size_t)z * 2048 + n0) * 1024;
    const u16* B2row = B1row + (size_t)1024 * 1024;
    const int lane = t & 63;
    const int wv = t >> 6, wm = wv & 1, wn = wv >> 1;
    const int quad = lane >> 4, l15 = lane & 15;

    floatx4 zero4 = {0.f, 0.f, 0.f, 0.f};
    floatx4 acc1[4][4], acc2[4][4];
#pragma unroll
    for (int i = 0; i < 4; ++i)
#pragma unroll
        for (int j = 0; j < 4; ++j) { acc1[i][j] = zero4; acc2[i][j] = zero4; }

    for (int k0 = 0; k0 < 1024; k0 += 64) {
        __syncthreads();
        stage_tile(Arow, k0, lA, t);
        stage_tile(B1row, k0, lB1, t);
        stage_tile(B2row, k0, lB2, t);
        __syncthreads();
#pragma unroll
        for (int kc = 0; kc < 2; ++kc) {
            short8 af[4], bf1[4], bf2[4];
#pragma unroll
            for (int mi = 0; mi < 4; ++mi) {
                int m = wm * 64 + mi * 16 + l15;
                int off = m * 64 + (((kc * 4 + quad) ^ (m & 7)) * 8);
                af[mi] = *(const short8*)&lA[off];
            }
#pragma unroll
            for (int ni = 0; ni < 4; ++ni) {
                int n = wn * 64 + ni * 16 + l15;
                int off = n * 64 + (((kc * 4 + quad) ^ (n & 7)) * 8);
                bf1[ni] = *(const short8*)&lB1[off];
                bf2[ni] = *(const short8*)&lB2[off];
            }
#pragma unroll
            for (int mi = 0; mi < 4; ++mi)
#pragma unroll
                for (int ni = 0; ni < 4; ++ni) {
                    acc1[mi][ni] = __builtin_amdgcn_mfma_f32_16x16x32_bf16(af[mi], bf1[ni], acc1[mi][ni], 0, 0, 0);
                    acc2[mi][ni] = __builtin_amdgcn_mfma_f32_16x16x32_bf16(af[mi], bf2[ni], acc2[mi][ni], 0, 0, 0);
                }
        }
    }
#pragma unroll
    for (int mi = 0; mi < 4; ++mi)
#pragma unroll
        for (int ni = 0; ni < 4; ++ni)
#pragma unroll
            for (int r = 0; r < 4; ++r) {
                int m = wm * 64 + mi * 16 + quad * 4 + r;
                int n = wn * 64 + ni * 16 + l15;
                float c1 = acc1[mi][ni][r], c2 = acc2[mi][ni][r];
                float v = SILU_FIRST ? silu_f(c1) * c2 : c1 * silu_f(c2);
                act[(size_t)(zb + bm0 + m) * 1024 + n0 + n] = f2b(v);
            }
}

template <bool SCATTER>
__global__ __launch_bounds__(256, 2)
void gemm2_mfma(const u16* __restrict__ A, int zstride,
                const u16* __restrict__ W2t,
                const int* __restrict__ slot_token, const float* __restrict__ slot_w,
                float* __restrict__ out, int out_row0, int e_base) {
    __shared__ u16 lA[128 * 64];
    __shared__ u16 lB[128 * 64];
    __shared__ int s_tok[128];
    __shared__ float s_w[128];
    const int t = threadIdx.x;
    const int n0 = blockIdx.x * 128;
    const int bm0 = blockIdx.y * 128;
    const int z = blockIdx.z;
    const int zb = z * zstride;
    const u16* Arow = A + (size_t)(zb + bm0) * 1024;
    const u16* Brow = W2t + ((size_t)z * 1024 + n0) * 1024;
    const int lane = t & 63;
    const int wv = t >> 6, wm = wv & 1, wn = wv >> 1;
    const int quad = lane >> 4, l15 = lane & 15;

    if (SCATTER && t < 128) {
        int gi = (e_base + z) * 2048 + bm0 + t;
        s_tok[t] = slot_token[gi];
        s_w[t] = slot_w[gi];
    }

    floatx4 zero4 = {0.f, 0.f, 0.f, 0.f};
    floatx4 acc[4][4];
#pragma unroll
    for (int i = 0; i < 4; ++i)
#pragma unroll
        for (int j = 0; j < 4; ++j) acc[i][j] = zero4;

    for (int k0 = 0; k0 < 1024; k0 += 64) {
        __syncthreads();
        stage_tile(Arow, k0, lA, t);
        stage_tile(Brow, k0, lB, t);
        __syncthreads();
#pragma unroll
        for (int kc = 0; kc < 2; ++kc) {
            short8 af[4], bf[4];
#pragma unroll
            for (int mi = 0; mi < 4; ++mi) {
                int m = wm * 64 + mi * 16 + l15;
                int off = m * 64 + (((kc * 4 + quad) ^ (m & 7)) * 8);
                af[mi] = *(const short8*)&lA[off];
            }
#pragma unroll
            for (int ni = 0; ni < 4; ++ni) {
                int n = wn * 64 + ni * 16 + l15;
                int off = n * 64 + (((kc * 4 + quad) ^ (n & 7)) * 8);
                bf[ni] = *(const short8*)&lB[off];
            }
#pragma unroll
            for (int mi = 0; mi < 4; ++mi)
#pragma unroll
                for (int ni = 0; ni < 4; ++ni)
                    acc[mi][ni] = __builtin_amdgcn_mfma_f32_16x16x32_bf16(af[mi], bf[ni], acc[mi][ni], 0, 0, 0);
        }
    }
#pragma unroll
    for (int mi = 0; mi < 4; ++mi)
#pragma unroll
        for (int ni = 0; ni < 4; ++ni)
#pragma unroll
            for (int r = 0; r < 4; ++r) {
                int m = wm * 64 + mi * 16 + quad * 4 + r;
                int n = wn * 64 + ni * 16 + l15;
                float c = acc[mi][ni][r];
                if (SCATTER) {
                    atomicAdd(&out[(size_t)s_tok[m] * 1024 + n0 + n], c * s_w[m]);
                } else {
                    out[(size_t)(out_row0 + bm0 + m) * 1024 + n0 + n] = c;
                }
            }
}

// ---------------- host launcher ----------------

extern "C" void kernel_launch(void* const* d_in, const int* in_sizes, int n_in,
                              void* d_out, int out_size, void* d_ws, size_t ws_size,
                              hipStream_t stream) {
    const float* hidden   = (const float*)d_in[0];
    const float* hsu      = (const float*)d_in[1];
    const float* timestep = (const float*)d_in[2];
    const float* gate_w   = (const float*)d_in[3];
    const float* gate_up  = (const float*)d_in[4];
    const float* down     = (const float*)d_in[5];
    const float* sh_gu    = (const float*)d_in[6];
    const float* sh_dn    = (const float*)d_in[7];
    float* out = (float*)d_out;

    char* p = (char*)d_ws;
    auto alloc = [&](size_t bytes) { char* r = p; p += (bytes + 255) & ~(size_t)255; return r; };
    float* tlogit    = (float*)alloc((size_t)Bb * Ee * 4);
    float* scores    = (float*)alloc((size_t)Bb * Ee * Ss * 4);
    int*   sel_idx   = (int*)  alloc((size_t)Bb * Ee * CAPk * 4);
    float* sel_gate  = (float*)alloc((size_t)Bb * Ee * CAPk * 4);
    float* sums      = (float*)alloc((size_t)Bb * Ss * 4);
    int*   slot_token= (int*)  alloc((size_t)Ee * Bb * CAPk * 4);
    float* slot_w    = (float*)alloc((size_t)Ee * Bb * CAPk * 4);
    char* phase = p;
    long long avail = (long long)((char*)d_ws + ws_size - phase);
    if (avail < 0) avail = 0;

    // --- router ---
    tlogit_kernel<<<Bb * Ee, 64, 0, stream>>>(timestep, gate_w, tlogit);
    router_scores<<<(Bb * Ss) / 64, 256, 0, stream>>>(hsu, gate_w, tlogit, scores);
    topk_kernel<<<Bb * Ee, 256, 0, stream>>>(scores, sel_idx, sel_gate);
    zero_kernel<<<(Bb * Ss + 255) / 256, 256, 0, stream>>>(sums, Bb * Ss);
    accum_kernel<<<(Bb * Ee * CAPk) / 256, 256, 0, stream>>>(sel_idx, sel_gate, sums);
    finalize_kernel<<<(Bb * Ee * CAPk) / 256, 256, 0, stream>>>(sel_idx, sel_gate, sums,
                                                                slot_token, slot_w);

    // --- shared expert phase (phase scratch: Xb | Wt1s | Wt2s | actS) ---
    {
        u16* Xb   = (u16*)phase;                       // 16384*1024 bf16 = 32 MB
        u16* Wt1s = Xb + (size_t)16384 * 1024;         // 2048*1024 bf16 = 4 MB
        u16* Wt2s = Wt1s + (size_t)2048 * 1024;        // 1024*1024 bf16 = 2 MB
        u16* actS = Wt2s + (size_t)1024 * 1024;
        long long fixed = ((long long)16384 * 1024 + 2048 * 1024 + 1024 * 1024) * 2;
        long long room = (avail - fixed) / 2048;       // act rows
        room &= ~127LL;
        int R = (int)(room > 16384 ? 16384 : room);
        if (R < 128) R = 128;

        convert_bf16<<<16384, 256, 0, stream>>>(hidden, Xb);
        transpose_bf16<<<dim3(64, 32, 1), 256, 0, stream>>>(sh_gu, Wt1s, 2048, 0, 0);
        transpose_bf16<<<dim3(32, 32, 1), 256, 0, stream>>>(sh_dn, Wt2s, 1024, 0, 0);
        for (int r0 = 0; r0 < Bb * Ss; r0 += R) {
            int cur = Bb * Ss - r0; if (cur > R) cur = R;
            gemm1_mfma<false><<<dim3(8, cur / 128, 1), 256, 0, stream>>>(Xb, r0, 0, Wt1s, actS);
            gemm2_mfma<false><<<dim3(8, cur / 128, 1), 256, 0, stream>>>(actS, 0, Wt2s,
                                                                         nullptr, nullptr, out, r0, 0);
        }
    }

    // --- routed experts phase (reuse phase scratch: Ag | Wt1r | Wt2r | actR) ---
    {
        const long long per_e = ((long long)2048 * 1024 * 3 + 1024 * 1024) * 2;  // 14 MB
        int g = (int)(avail / per_e);
        if (g < 1) g = 1;
        if (g > Ee) g = Ee;
        u16* Ag   = (u16*)phase;
        u16* Wt1r = Ag   + (size_t)g * 2048 * 1024;
        u16* Wt2r = Wt1r + (size_t)g * 2048 * 1024;
        u16* actR = Wt2r + (size_t)g * 1024 * 1024;

        for (int e0 = 0; e0 < Ee; e0 += g) {
            int cg = Ee - e0; if (cg > g) cg = g;
            gather_bf16<<<cg * 2048, 256, 0, stream>>>(hidden, slot_token, Ag, e0);
            transpose_bf16<<<dim3(64, 32, cg), 256, 0, stream>>>(
                gate_up + (size_t)e0 * 2097152, Wt1r, 2048, 2097152, 2097152);
            transpose_bf16<<<dim3(32, 32, cg), 256, 0, stream>>>(
                down + (size_t)e0 * 1048576, Wt2r, 1024, 1048576, 1048576);
            gemm1_mfma<true><<<dim3(8, 16, cg), 256, 0, stream>>>(Ag, 0, 2048, Wt1r, actR);
            gemm2_mfma<true><<<dim3(8, 16, cg), 256, 0, stream>>>(actR, 2048, Wt2r,
                                                                  slot_token, slot_w, out, 0, e0);
        }
    }
}